// Round 14
// baseline (236.168 us; speedup 1.0000x reference)
//
#include <hip/hip_runtime.h>

// ConvLSTM2D MI355X, R14: R13 skeleton (persistent + local 8-neighbor sync)
// + 16 waves/block (4/SIMD TLP), X-compute-before-poll, prep_x bf16.
// Block = (b, 16x8 tile) x 256 co, 1024 thr. Wave = 32 px x 64 co (acc 2x4).
// Step: computeX(9) -> poll(t) -> import ring h(t-1) -> computeH(18) ->
// gates (out + c-reg + interior h->LDS) -> export ring -> flag -> stageX(t+1).
// h interior never touches global; ring via sc0sc1 16B ops. Weights L2-warm.

typedef __attribute__((ext_vector_type(8))) short short8v;
typedef __attribute__((ext_vector_type(4))) float f32x4;
typedef __attribute__((ext_vector_type(4))) unsigned int u32x4;
typedef unsigned short u16;

__device__ __forceinline__ u16 f2bf(float x) {
    union { float f; unsigned u; } a; a.f = x;
    unsigned r = a.u + 0x7FFFu + ((a.u >> 16) & 1u);   // RNE
    return (u16)(r >> 16);
}
__device__ __forceinline__ float sigf(float x) { return 1.0f / (1.0f + __expf(-x)); }
__device__ __forceinline__ float tanhf_(float x) {
    float e = __expf(2.0f * x);
    return 1.0f - 2.0f / (e + 1.0f);
}

// ---- prep: x f32 -> bf16 ----
__global__ __launch_bounds__(256)
void prep_x(const float* __restrict__ x, u16* __restrict__ xb) {
    size_t i = (size_t)blockIdx.x * 256 + threadIdx.x;
    for (; i < 2621440u; i += (size_t)2048 * 256) {
        float4 v = ((const float4*)x)[i];
        union { u16 u[4]; uint2 q; } o;
        o.u[0] = f2bf(v.x); o.u[1] = f2bf(v.y);
        o.u[2] = f2bf(v.z); o.u[3] = f2bf(v.w);
        ((uint2*)xb)[i] = o.q;
    }
}

// ---- prep: weights -> staged layout + zero flags ----
__global__ __launch_bounds__(256)
void prep_w(const float* __restrict__ kern, const float* __restrict__ rk,
            u16* __restrict__ wt_in, u16* __restrict__ wt_rk,
            unsigned* __restrict__ flags) {
    int idx = blockIdx.x * 256 + threadIdx.x;
    if (blockIdx.x == 0) flags[threadIdx.x] = 0u;
    if (idx >= 82944) return;
    const float* s;
    u16* dst;
    if (idx < 9216) {
        int co = idx & 255, ckb = idx >> 8;          // 0..35 = tap*4+kb
        int tap = ckb >> 2, kb = ckb & 3;
        s = kern + (size_t)((tap << 5) + (kb << 3)) * 256 + co;
        dst = wt_in + (size_t)idx * 8;
    } else {
        int j = idx - 9216;
        int co = j & 255, rest = j >> 8;             // 0..287
        int kb = rest & 3, gc = rest >> 2;           // gc = g*18 + cc
        int g = gc / 18, cc = gc - g * 18;
        int tap = cc >> 1;
        int cib = (cc & 1) << 5;
        s = rk + (size_t)(((g * 9 + tap) << 6) + cib + (kb << 3)) * 256 + co;
        dst = wt_rk + (size_t)j * 8;
    }
    union { u16 u[8]; uint4 q; } o;
    #pragma unroll
    for (int i = 0; i < 8; ++i) o.u[i] = f2bf(s[i * 256]);
    *(uint4*)dst = o.q;
}

// ---- persistent fused conv + gates, all timesteps ----
__global__ __launch_bounds__(1024)
void lstm_all(const u16* __restrict__ xb,     // (8,10,64,64,32) bf16
              const u16* __restrict__ wt_in, const u16* __restrict__ wt_rk,
              const float* __restrict__ bias, const int* __restrict__ labels,
              u16* __restrict__ hb0, u16* __restrict__ hb1,  // h ring bufs
              float* __restrict__ out, unsigned* __restrict__ flags)
{
    // X halo @0: [kb4][180][8] (5760 shorts); H halo @5760: [kb8][180][8]
    __shared__ short hal[17280];   // 34,560 B

    const int tid  = threadIdx.x;
    const int lane = tid & 63;
    const int w    = tid >> 6;                 // 0..15
    const int pxq  = w >> 2;                   // 4-row band (0..3)
    const int wq   = w & 3;                    // f-slice of 16
    const int b    = blockIdx.x >> 5;
    const int tile = blockIdx.x & 31;
    const int ty = tile >> 3, tx = tile & 7;
    const int y0 = ty << 4, x0 = tx << 3;
    const int g = labels[b];

    const int co_l = lane & 15;
    const int kbl  = lane >> 4;
    const int prow = (lane & 15) >> 3, pcol = lane & 7;
    const int f = (wq << 4) + co_l;

    float bv[4];
    #pragma unroll
    for (int n = 0; n < 4; ++n)
        bv[n] = bias[(g << 8) + (n << 6) + f];

    int aoffm[2];
    #pragma unroll
    for (int mf = 0; mf < 2; ++mf)
        aoffm[mf] = ((pxq << 2) + (mf << 1) + prow) * 10 + pcol;

    // out offsets + interior-LDS offsets for the 8 px this thread owns
    int poff[2][4], loff[2][4];
    #pragma unroll
    for (int mf = 0; mf < 2; ++mf)
        #pragma unroll
        for (int rr = 0; rr < 4; ++rr) {
            int pf = (kbl << 2) + rr;
            int ly = (pxq << 2) + (mf << 1) + (pf >> 3);
            int lx = pf & 7;
            poff[mf][rr] = ((((y0 + ly) << 6) + x0 + lx) << 6) + f;
            loff[mf][rr] = 5760 + (f >> 3) * 1440 + ((ly + 1) * 10 + lx + 1) * 8 + (f & 7);
        }

    float cst[2][4];
    #pragma unroll
    for (int mf = 0; mf < 2; ++mf)
        #pragma unroll
        for (int rr = 0; rr < 4; ++rr) cst[mf][rr] = 0.0f;

    const u16* xsrc = xb + ((size_t)b * 10 << 17);
    float*     ob0  = out + ((size_t)b * 10 << 18);
    unsigned*  myfl = flags + (b << 5) + tile;

    // zero H halo (out-of-image ring cells stay 0 forever); stage X(0)
    for (int s = tid; s < 1440; s += 1024)
        *(short8v*)&hal[5760 + s * 8] = (short8v){0,0,0,0,0,0,0,0};
    if (tid < 720) {
        int pos = tid >> 2, kb = tid & 3;
        int hy = pos / 10, hx = pos - hy * 10;
        int gy = y0 + hy - 1, gx = x0 + hx - 1;
        short8v v = (short8v){0,0,0,0,0,0,0,0};
        if ((unsigned)gy < 64u && (unsigned)gx < 64u)
            v = *(const short8v*)&xsrc[(((gy << 6) + gx) << 5) + (kb << 3)];
        *(short8v*)&hal[kb * 1440 + pos * 8] = v;
    }
    __syncthreads();

    for (int t = 0; t < 10; ++t) {
        u16* hw = ((t & 1) ? hb1 : hb0) + ((size_t)b << 18);   // h(t) buffer

        f32x4 acc[2][4];
        #pragma unroll
        for (int n = 0; n < 4; ++n)
            #pragma unroll
            for (int mf = 0; mf < 2; ++mf)
                acc[mf][n] = (f32x4){bv[n], bv[n], bv[n], bv[n]};

        // ---- phase X: 9 chunks (h-independent; runs before poll) ----
        #pragma unroll 3
        for (int tap = 0; tap < 9; ++tap) {
            const int koff = (tap / 3) * 10 + (tap % 3);
            const u16* wb = wt_in + (size_t)((((tap << 2) + kbl) << 8) + f) * 8;
            short8v bfr[4], af[2];
            #pragma unroll
            for (int n = 0; n < 4; ++n)
                bfr[n] = *(const short8v*)&wb[(size_t)n << 9];
            #pragma unroll
            for (int mf = 0; mf < 2; ++mf)
                af[mf] = *(const short8v*)&hal[kbl * 1440 + (aoffm[mf] + koff) * 8];
            #pragma unroll
            for (int mf = 0; mf < 2; ++mf)
                #pragma unroll
                for (int n = 0; n < 4; ++n)
                    acc[mf][n] = __builtin_amdgcn_mfma_f32_16x16x32_bf16(af[mf], bfr[n], acc[mf][n], 0, 0, 0);
        }

        if (t > 0) {
            // ---- poll 8 neighbor flags (wave 0): need h(t-1) exported ----
            if (tid < 64) {
                bool valid = false; int fidx = 0;
                if (tid < 8) {
                    int kk = tid + (tid >= 4);       // 0..8 skipping center
                    int nty = ty + kk / 3 - 1, ntx = tx + kk % 3 - 1;
                    valid = (unsigned)nty < 4u && (unsigned)ntx < 8u;
                    fidx = (b << 5) + (nty << 3) + ntx;
                }
                unsigned tgt = (unsigned)t;
                int guard = 0;
                for (;;) {
                    unsigned vv = tgt;
                    if (valid)
                        vv = __hip_atomic_load(flags + fidx, __ATOMIC_RELAXED,
                                               __HIP_MEMORY_SCOPE_SYSTEM);
                    if (__all(vv >= tgt)) break;
                    if (++guard > (1 << 18)) break;
                    __builtin_amdgcn_s_sleep(2);
                }
            }
            __syncthreads();   // poll done -> neighbors' h(t-1) visible

            // ---- import ring h(t-1): 52 px x 8 units, sc0sc1 16B ----
            if (tid < 416) {
                const u16* hr = ((t & 1) ? hb0 : hb1) + ((size_t)b << 18);
                int posr = tid >> 3, kb = tid & 7;
                int hy, hx;
                if (posr < 10)      { hy = 0;  hx = posr; }
                else if (posr < 20) { hy = 17; hx = posr - 10; }
                else { int v = posr - 20; hy = 1 + (v >> 1); hx = (v & 1) * 9; }
                int gy = y0 + hy - 1, gx = x0 + hx - 1;
                bool inb = (unsigned)gy < 64u && (unsigned)gx < 64u;
                const u16* ga = inb ? (hr + (((gy << 6) + gx) << 6) + (kb << 3)) : hr;
                u32x4 v;
                asm volatile("global_load_dwordx4 %0, %1, off sc0 sc1"
                             : "=v"(v) : "v"(ga) : "memory");
                asm volatile("s_waitcnt vmcnt(0)" ::: "memory");
                __builtin_amdgcn_sched_barrier(0);
                if (!inb) v = (u32x4){0u, 0u, 0u, 0u};
                *(u32x4*)&hal[5760 + kb * 1440 + (hy * 10 + hx) * 8] = v;
            }
            __syncthreads();   // ring in LDS

            // ---- phase H: 18 chunks ----
            #pragma unroll 3
            for (int c = 0; c < 18; ++c) {
                const int tap = c >> 1;
                const int koff = (tap / 3) * 10 + (tap % 3);
                const u16* wb = wt_rk + (size_t)(((((g * 18 + c) << 2) + kbl) << 8) + f) * 8;
                short8v bfr[4], af[2];
                #pragma unroll
                for (int n = 0; n < 4; ++n)
                    bfr[n] = *(const short8v*)&wb[(size_t)n << 9];
                const int abase = 5760 + (((c & 1) << 2) + kbl) * 1440;
                #pragma unroll
                for (int mf = 0; mf < 2; ++mf)
                    af[mf] = *(const short8v*)&hal[abase + (aoffm[mf] + koff) * 8];
                #pragma unroll
                for (int mf = 0; mf < 2; ++mf)
                    #pragma unroll
                    for (int n = 0; n < 4; ++n)
                        acc[mf][n] = __builtin_amdgcn_mfma_f32_16x16x32_bf16(af[mf], bfr[n], acc[mf][n], 0, 0, 0);
            }
        }
        __syncthreads();   // sync1: H-LDS reads (h(t-1)) complete

        // ---- gates + out store + h(t) interior -> LDS ----
        float* ob = ob0 + ((size_t)t << 18);
        #pragma unroll
        for (int mf = 0; mf < 2; ++mf) {
            #pragma unroll
            for (int rr = 0; rr < 4; ++rr) {
                float zi = acc[mf][0][rr], zf = acc[mf][1][rr];
                float zg = acc[mf][2][rr], zo = acc[mf][3][rr];
                float cn = sigf(zf) * cst[mf][rr] + sigf(zi) * tanhf_(zg);
                float hn = sigf(zo) * tanhf_(cn);
                cst[mf][rr] = cn;
                ob[poff[mf][rr]] = hn;
                hal[loff[mf][rr]] = (short)f2bf(hn);
            }
        }
        __syncthreads();   // sync2: interior h(t) in LDS

        if (t < 9) {
            // ---- ring export: 44 boundary px x 8 units, sc0sc1 16B ----
            if (tid < 352) {
                int pxr = tid >> 3, kb = tid & 7;
                int dy, dx;
                if (pxr < 8)       { dy = 0;  dx = pxr; }
                else if (pxr < 16) { dy = 15; dx = pxr - 8; }
                else { int v = pxr - 16; dy = 1 + (v >> 1); dx = (v & 1) * 7; }
                u32x4 v = *(const u32x4*)&hal[5760 + kb * 1440 + ((dy + 1) * 10 + dx + 1) * 8];
                const u16* ga = hw + ((((y0 + dy) << 6) + x0 + dx) << 6) + (kb << 3);
                asm volatile("global_store_dwordx4 %0, %1, off sc0 sc1"
                             :: "v"(ga), "v"(v) : "memory");
            }
            asm volatile("s_waitcnt vmcnt(0)" ::: "memory");
            __syncthreads();   // sync3: ring stores drained (all threads)
            if (tid == 0)
                __hip_atomic_fetch_add(myfl, 1u, __ATOMIC_RELAXED,
                                       __HIP_MEMORY_SCOPE_SYSTEM);

            // ---- stage X(t+1) ----
            if (tid < 720) {
                const u16* src = xsrc + ((size_t)(t + 1) << 17);
                int pos = tid >> 2, kb = tid & 3;
                int hy = pos / 10, hx = pos - hy * 10;
                int gy = y0 + hy - 1, gx = x0 + hx - 1;
                short8v v = (short8v){0,0,0,0,0,0,0,0};
                if ((unsigned)gy < 64u && (unsigned)gx < 64u)
                    v = *(const short8v*)&src[(((gy << 6) + gx) << 5) + (kb << 3)];
                *(short8v*)&hal[kb * 1440 + pos * 8] = v;
            }
            __syncthreads();   // sync4: X(t+1) staged
        }
    }
}

extern "C" void kernel_launch(void* const* d_in, const int* in_sizes, int n_in,
                              void* d_out, int out_size, void* d_ws, size_t ws_size,
                              hipStream_t stream)
{
    const float* x    = (const float*)d_in[0];
    const int*   lbl  = (const int*)  d_in[1];
    const float* kern = (const float*)d_in[2];
    const float* rk   = (const float*)d_in[3];
    const float* bias = (const float*)d_in[4];
    float* out = (float*)d_out;

    // ws: xb 20.97MB | hb0 4.19 | hb1 4.19 | wt_in 0.147 | wt_rk 1.18 | flags
    u16* xb    = (u16*)d_ws;
    u16* hb0   = xb + 10485760;
    u16* hb1   = hb0 + 2097152;
    u16* wt_in = hb1 + 2097152;
    u16* wt_rk = wt_in + 73728;
    unsigned* flags = (unsigned*)(wt_rk + 589824);

    hipLaunchKernelGGL(prep_x, dim3(2048), dim3(256), 0, stream, x, xb);
    hipLaunchKernelGGL(prep_w, dim3(324), dim3(256), 0, stream,
                       kern, rk, wt_in, wt_rk, flags);

    void* args[] = { (void*)&xb, (void*)&wt_in, (void*)&wt_rk, (void*)&bias,
                     (void*)&lbl, (void*)&hb0, (void*)&hb1, (void*)&out,
                     (void*)&flags };
    (void)hipLaunchCooperativeKernel((const void*)lstm_all, dim3(256), dim3(1024),
                                     args, 0, stream);
}

// Round 15
// 201.026 us; speedup vs baseline: 1.1748x; 1.1748x over previous
//
#include <hip/hip_runtime.h>

// ConvLSTM2D MI355X, R15: R13 base (persistent + local 8-neighbor sync, 512thr)
// + (1) H-halo kb-stride 1440->1448 shorts (kills 4-way ds_write_b16 bank
// conflicts from gate interior-h writes; 1.78e7 conflict cycles in R13/R14),
// (2) prep_x bf16 (staging = pure 16B copy), (3) poll/import moved AFTER the
// h-independent X chunks (straggler wait hides under X compute).
// Block = (b, 16x8 tile) x 256 co, 8 waves. Wave = 64px x 64co, acc 4x4.
// h interior never touches global; ring via sc0sc1 16B; weights/x L2-warm;
// c in registers.

typedef __attribute__((ext_vector_type(8))) short short8v;
typedef __attribute__((ext_vector_type(4))) float f32x4;
typedef __attribute__((ext_vector_type(4))) unsigned int u32x4;
typedef unsigned short u16;

#define HS 1448            // shorts per kb block in H halo (181 x 16B slots)
#define HB 5760            // H halo base (shorts); X halo = [0, 5760)

__device__ __forceinline__ u16 f2bf(float x) {
    union { float f; unsigned u; } a; a.f = x;
    unsigned r = a.u + 0x7FFFu + ((a.u >> 16) & 1u);   // RNE
    return (u16)(r >> 16);
}
__device__ __forceinline__ float sigf(float x) { return 1.0f / (1.0f + __expf(-x)); }
__device__ __forceinline__ float tanhf_(float x) {
    float e = __expf(2.0f * x);
    return 1.0f - 2.0f / (e + 1.0f);
}

// ---- prep: x f32 -> bf16 ----
__global__ __launch_bounds__(256)
void prep_x(const float* __restrict__ x, u16* __restrict__ xb) {
    size_t i = (size_t)blockIdx.x * 256 + threadIdx.x;
    for (; i < 2621440u; i += (size_t)2048 * 256) {
        float4 v = ((const float4*)x)[i];
        union { u16 u[4]; uint2 q; } o;
        o.u[0] = f2bf(v.x); o.u[1] = f2bf(v.y);
        o.u[2] = f2bf(v.z); o.u[3] = f2bf(v.w);
        ((uint2*)xb)[i] = o.q;
    }
}

// ---- prep: weights -> staged layout + zero flags ----
__global__ __launch_bounds__(256)
void prep_w(const float* __restrict__ kern, const float* __restrict__ rk,
            u16* __restrict__ wt_in, u16* __restrict__ wt_rk,
            unsigned* __restrict__ flags) {
    int idx = blockIdx.x * 256 + threadIdx.x;
    if (blockIdx.x == 0) flags[threadIdx.x] = 0u;
    if (idx >= 82944) return;
    const float* s;
    u16* dst;
    if (idx < 9216) {
        int co = idx & 255, ckb = idx >> 8;          // 0..35 = tap*4+kb
        int tap = ckb >> 2, kb = ckb & 3;
        s = kern + (size_t)((tap << 5) + (kb << 3)) * 256 + co;
        dst = wt_in + (size_t)idx * 8;
    } else {
        int j = idx - 9216;
        int co = j & 255, rest = j >> 8;             // 0..287
        int kb = rest & 3, gc = rest >> 2;           // gc = g*18 + cc
        int g = gc / 18, cc = gc - g * 18;
        int tap = cc >> 1;
        int cib = (cc & 1) << 5;
        s = rk + (size_t)(((g * 9 + tap) << 6) + cib + (kb << 3)) * 256 + co;
        dst = wt_rk + (size_t)j * 8;
    }
    union { u16 u[8]; uint4 q; } o;
    #pragma unroll
    for (int i = 0; i < 8; ++i) o.u[i] = f2bf(s[i * 256]);
    *(uint4*)dst = o.q;
}

__device__ __forceinline__ void stageX(const u16* __restrict__ src,
                                       short* __restrict__ halX,
                                       int tid, int y0, int x0) {
    #pragma unroll 2
    for (int s = tid; s < 720; s += 512) {
        int pos = s >> 2, kb = s & 3;
        int hy = pos / 10, hx = pos - hy * 10;
        int gy = y0 + hy - 1, gx = x0 + hx - 1;
        short8v v = (short8v){0,0,0,0,0,0,0,0};
        if ((unsigned)gy < 64u && (unsigned)gx < 64u)
            v = *(const short8v*)&src[(((gy << 6) + gx) << 5) + (kb << 3)];
        *(short8v*)&halX[kb * 1440 + pos * 8] = v;
    }
}

// ---- persistent fused conv + gates, all timesteps ----
__global__ __launch_bounds__(512)
void lstm_all(const u16* __restrict__ xb,     // (8,10,64,64,32) bf16
              const u16* __restrict__ wt_in, const u16* __restrict__ wt_rk,
              const float* __restrict__ bias, const int* __restrict__ labels,
              u16* __restrict__ hb0, u16* __restrict__ hb1,  // h ring bufs
              float* __restrict__ out, unsigned* __restrict__ flags)
{
    // X halo @0: [kb4][180][8] (5760 shorts); H halo @5760: [kb8][HS=1448]
    __shared__ short hal[HB + 8 * HS];   // 17344 shorts = 34,688 B

    const int tid  = threadIdx.x;
    const int lane = tid & 63;
    const int w    = tid >> 6;
    const int pxh  = w >> 2;                   // pixel half (rows 0-7 / 8-15)
    const int wq   = w & 3;                    // f-slice of 16
    const int b    = blockIdx.x >> 5;
    const int tile = blockIdx.x & 31;
    const int ty = tile >> 3, tx = tile & 7;
    const int y0 = ty << 4, x0 = tx << 3;
    const int g = labels[b];

    const int co_l = lane & 15;
    const int kbl  = lane >> 4;
    const int prow = (lane & 15) >> 3, pcol = lane & 7;
    const int f = (wq << 4) + co_l;

    float bv[4];
    #pragma unroll
    for (int n = 0; n < 4; ++n)
        bv[n] = bias[(g << 8) + (n << 6) + f];

    int aoffm[4];
    #pragma unroll
    for (int m = 0; m < 4; ++m)
        aoffm[m] = ((pxh << 3) + (m << 1) + prow) * 10 + pcol;

    int poff[4][4], loff[4][4];
    #pragma unroll
    for (int m = 0; m < 4; ++m)
        #pragma unroll
        for (int rr = 0; rr < 4; ++rr) {
            int pf = (kbl << 2) + rr;
            int ly = (pxh << 3) + (m << 1) + (pf >> 3);
            int lx = pf & 7;
            poff[m][rr] = ((((y0 + ly) << 6) + x0 + lx) << 6) + f;
            loff[m][rr] = HB + (f >> 3) * HS + ((ly + 1) * 10 + lx + 1) * 8 + (f & 7);
        }

    float cst[4][4];
    #pragma unroll
    for (int m = 0; m < 4; ++m)
        #pragma unroll
        for (int rr = 0; rr < 4; ++rr) cst[m][rr] = 0.0f;

    const u16* xsrc = xb + ((size_t)b * 10 << 17);
    float*     ob0  = out + ((size_t)b * 10 << 18);
    unsigned*  myfl = flags + (b << 5) + tile;

    // zero H halo (incl. pad slots; out-of-image ring cells stay 0 forever)
    for (int s = tid; s < 1448; s += 512)
        *(short8v*)&hal[HB + s * 8] = (short8v){0,0,0,0,0,0,0,0};
    stageX(xsrc, hal, tid, y0, x0);
    __syncthreads();

    for (int t = 0; t < 10; ++t) {
        u16* hw = ((t & 1) ? hb1 : hb0) + ((size_t)b << 18);   // h(t) buffer

        f32x4 acc[4][4];
        #pragma unroll
        for (int n = 0; n < 4; ++n)
            #pragma unroll
            for (int m = 0; m < 4; ++m)
                acc[m][n] = (f32x4){bv[n], bv[n], bv[n], bv[n]};

        // ---- phase X: 9 chunks (h-independent) ----
        #pragma unroll 3
        for (int tap = 0; tap < 9; ++tap) {
            const int koff = (tap / 3) * 10 + (tap % 3);
            const u16* wb = wt_in + (size_t)((((tap << 2) + kbl) << 8) + f) * 8;
            short8v bfr[4], af[4];
            #pragma unroll
            for (int n = 0; n < 4; ++n)
                bfr[n] = *(const short8v*)&wb[(size_t)n << 9];
            #pragma unroll
            for (int m = 0; m < 4; ++m)
                af[m] = *(const short8v*)&hal[kbl * 1440 + (aoffm[m] + koff) * 8];
            #pragma unroll
            for (int m = 0; m < 4; ++m)
                #pragma unroll
                for (int n = 0; n < 4; ++n)
                    acc[m][n] = __builtin_amdgcn_mfma_f32_16x16x32_bf16(af[m], bfr[n], acc[m][n], 0, 0, 0);
        }

        if (t > 0) {
            // ---- poll 8 neighbor flags (wave 0): need h(t-1) exported ----
            if (tid < 64) {
                bool valid = false; int fidx = 0;
                if (tid < 8) {
                    int kk = tid + (tid >= 4);       // 0..8 skipping center
                    int nty = ty + kk / 3 - 1, ntx = tx + kk % 3 - 1;
                    valid = (unsigned)nty < 4u && (unsigned)ntx < 8u;
                    fidx = (b << 5) + (nty << 3) + ntx;
                }
                unsigned tgt = (unsigned)t;
                int guard = 0;
                for (;;) {
                    unsigned vv = tgt;
                    if (valid)
                        vv = __hip_atomic_load(flags + fidx, __ATOMIC_RELAXED,
                                               __HIP_MEMORY_SCOPE_SYSTEM);
                    if (__all(vv >= tgt)) break;
                    if (++guard > (1 << 18)) break;
                    __builtin_amdgcn_s_sleep(2);
                }
            }
            __syncthreads();   // neighbors' h(t-1) rings globally visible

            // ---- import ring h(t-1): 52 px x 8 units, sc0sc1 16B ----
            if (tid < 416) {
                const u16* hr = ((t & 1) ? hb0 : hb1) + ((size_t)b << 18);
                int posr = tid >> 3, kb = tid & 7;
                int hy, hx;
                if (posr < 10)      { hy = 0;  hx = posr; }
                else if (posr < 20) { hy = 17; hx = posr - 10; }
                else { int v = posr - 20; hy = 1 + (v >> 1); hx = (v & 1) * 9; }
                int gy = y0 + hy - 1, gx = x0 + hx - 1;
                bool inb = (unsigned)gy < 64u && (unsigned)gx < 64u;
                const u16* ga = inb ? (hr + (((gy << 6) + gx) << 6) + (kb << 3)) : hr;
                u32x4 v;
                asm volatile("global_load_dwordx4 %0, %1, off sc0 sc1"
                             : "=v"(v) : "v"(ga) : "memory");
                asm volatile("s_waitcnt vmcnt(0)" ::: "memory");
                __builtin_amdgcn_sched_barrier(0);
                if (!inb) v = (u32x4){0u, 0u, 0u, 0u};
                *(u32x4*)&hal[HB + kb * HS + (hy * 10 + hx) * 8] = v;
            }
            __syncthreads();   // ring in LDS

            // ---- phase H: 18 chunks ----
            #pragma unroll 3
            for (int c = 0; c < 18; ++c) {
                const int tap = c >> 1;
                const int koff = (tap / 3) * 10 + (tap % 3);
                const u16* wb = wt_rk + (size_t)(((((g * 18 + c) << 2) + kbl) << 8) + f) * 8;
                short8v bfr[4], af[4];
                #pragma unroll
                for (int n = 0; n < 4; ++n)
                    bfr[n] = *(const short8v*)&wb[(size_t)n << 9];
                const int abase = HB + (((c & 1) << 2) + kbl) * HS;
                #pragma unroll
                for (int m = 0; m < 4; ++m)
                    af[m] = *(const short8v*)&hal[abase + (aoffm[m] + koff) * 8];
                #pragma unroll
                for (int m = 0; m < 4; ++m)
                    #pragma unroll
                    for (int n = 0; n < 4; ++n)
                        acc[m][n] = __builtin_amdgcn_mfma_f32_16x16x32_bf16(af[m], bfr[n], acc[m][n], 0, 0, 0);
            }
        }
        __syncthreads();   // sync1: H-LDS (h(t-1)) reads complete

        // ---- gates + out store + h(t) interior -> LDS ----
        float* ob = ob0 + ((size_t)t << 18);
        #pragma unroll
        for (int m = 0; m < 4; ++m) {
            #pragma unroll
            for (int rr = 0; rr < 4; ++rr) {
                float zi = acc[m][0][rr], zf = acc[m][1][rr];
                float zg = acc[m][2][rr], zo = acc[m][3][rr];
                float cn = sigf(zf) * cst[m][rr] + sigf(zi) * tanhf_(zg);
                float hn = sigf(zo) * tanhf_(cn);
                cst[m][rr] = cn;
                ob[poff[m][rr]] = hn;
                hal[loff[m][rr]] = (short)f2bf(hn);
            }
        }
        __syncthreads();   // sync2: interior h(t) in LDS

        if (t < 9) {
            // ---- ring export: 44 boundary px x 8 units, sc0sc1 16B ----
            if (tid < 352) {
                int pxr = tid >> 3, kb = tid & 7;
                int dy, dx;
                if (pxr < 8)       { dy = 0;  dx = pxr; }
                else if (pxr < 16) { dy = 15; dx = pxr - 8; }
                else { int v = pxr - 16; dy = 1 + (v >> 1); dx = (v & 1) * 7; }
                u32x4 v = *(const u32x4*)&hal[HB + kb * HS + ((dy + 1) * 10 + dx + 1) * 8];
                const u16* ga = hw + ((((y0 + dy) << 6) + x0 + dx) << 6) + (kb << 3);
                asm volatile("global_store_dwordx4 %0, %1, off sc0 sc1"
                             :: "v"(ga), "v"(v) : "memory");
            }
            // ---- stage X(t+1) (overlaps export latency) ----
            stageX(xsrc + ((size_t)(t + 1) << 17), hal, tid, y0, x0);
            asm volatile("s_waitcnt vmcnt(0)" ::: "memory");  // exports drained
            __syncthreads();   // sync3: exports + X(t+1) staged
            if (tid == 0)
                __hip_atomic_fetch_add(myfl, 1u, __ATOMIC_RELAXED,
                                       __HIP_MEMORY_SCOPE_SYSTEM);
        }
    }
}

extern "C" void kernel_launch(void* const* d_in, const int* in_sizes, int n_in,
                              void* d_out, int out_size, void* d_ws, size_t ws_size,
                              hipStream_t stream)
{
    const float* x    = (const float*)d_in[0];
    const int*   lbl  = (const int*)  d_in[1];
    const float* kern = (const float*)d_in[2];
    const float* rk   = (const float*)d_in[3];
    const float* bias = (const float*)d_in[4];
    float* out = (float*)d_out;

    // ws: xb 20.97MB | hb0 4.19 | hb1 4.19 | wt_in 0.147 | wt_rk 1.18 | flags
    u16* xb    = (u16*)d_ws;
    u16* hb0   = xb + 10485760;
    u16* hb1   = hb0 + 2097152;
    u16* wt_in = hb1 + 2097152;
    u16* wt_rk = wt_in + 73728;
    unsigned* flags = (unsigned*)(wt_rk + 589824);

    hipLaunchKernelGGL(prep_x, dim3(2048), dim3(256), 0, stream, x, xb);
    hipLaunchKernelGGL(prep_w, dim3(324), dim3(256), 0, stream,
                       kern, rk, wt_in, wt_rk, flags);

    void* args[] = { (void*)&xb, (void*)&wt_in, (void*)&wt_rk, (void*)&bias,
                     (void*)&lbl, (void*)&hb0, (void*)&hb1, (void*)&out,
                     (void*)&flags };
    (void)hipLaunchCooperativeKernel((const void*)lstm_all, dim3(256), dim3(512),
                                     args, 0, stream);
}

// Round 17
// 175.911 us; speedup vs baseline: 1.3425x; 1.1428x over previous
//
#include <hip/hip_runtime.h>

// ConvLSTM2D MI355X, R17: R16 kernel body (8x8 tiles, 512 blocks x 256 thr,
// 2 independent blocks/CU), launch fixed: cooperative launch rejected >256
// blocks (R16 output never written); use REGULAR launch + capacity guarantee
// per guide §1: __launch_bounds__(256, 2) and grid = 2 x 256. Protocol is
// dispatch-order-independent (system-scope flags, bounded spin).
// Wave = 64px x 64co, acc 4x4, 27 K-chunks, weights global->regs (L2-warm).
// h interior stays in LDS; ring export 28px / import 36px via sc0sc1 16B.
// c in registers. Local 8-neighbor flag sync, X-compute-before-poll.

typedef __attribute__((ext_vector_type(8))) short short8v;
typedef __attribute__((ext_vector_type(4))) float f32x4;
typedef __attribute__((ext_vector_type(4))) unsigned int u32x4;
typedef unsigned short u16;

#define HS 808             // shorts per kb block in H halo (101 x 16B slots)
#define HB 3200            // H halo base (shorts); X halo = [0, 3200)

__device__ __forceinline__ u16 f2bf(float x) {
    union { float f; unsigned u; } a; a.f = x;
    unsigned r = a.u + 0x7FFFu + ((a.u >> 16) & 1u);   // RNE
    return (u16)(r >> 16);
}
__device__ __forceinline__ float sigf(float x) { return 1.0f / (1.0f + __expf(-x)); }
__device__ __forceinline__ float tanhf_(float x) {
    float e = __expf(2.0f * x);
    return 1.0f - 2.0f / (e + 1.0f);
}

// ---- prep: x f32 -> bf16 ----
__global__ __launch_bounds__(256)
void prep_x(const float* __restrict__ x, u16* __restrict__ xb) {
    size_t i = (size_t)blockIdx.x * 256 + threadIdx.x;
    for (; i < 2621440u; i += (size_t)2048 * 256) {
        float4 v = ((const float4*)x)[i];
        union { u16 u[4]; uint2 q; } o;
        o.u[0] = f2bf(v.x); o.u[1] = f2bf(v.y);
        o.u[2] = f2bf(v.z); o.u[3] = f2bf(v.w);
        ((uint2*)xb)[i] = o.q;
    }
}

// ---- prep: weights -> staged layout + zero flags ----
__global__ __launch_bounds__(256)
void prep_w(const float* __restrict__ kern, const float* __restrict__ rk,
            u16* __restrict__ wt_in, u16* __restrict__ wt_rk,
            unsigned* __restrict__ flags) {
    int idx = blockIdx.x * 256 + threadIdx.x;
    if (idx < 512) flags[idx] = 0u;
    if (idx >= 82944) return;
    const float* s;
    u16* dst;
    if (idx < 9216) {
        int co = idx & 255, ckb = idx >> 8;          // 0..35 = tap*4+kb
        int tap = ckb >> 2, kb = ckb & 3;
        s = kern + (size_t)((tap << 5) + (kb << 3)) * 256 + co;
        dst = wt_in + (size_t)idx * 8;
    } else {
        int j = idx - 9216;
        int co = j & 255, rest = j >> 8;             // 0..287
        int kb = rest & 3, gc = rest >> 2;           // gc = g*18 + cc
        int g = gc / 18, cc = gc - g * 18;
        int tap = cc >> 1;
        int cib = (cc & 1) << 5;
        s = rk + (size_t)(((g * 9 + tap) << 6) + cib + (kb << 3)) * 256 + co;
        dst = wt_rk + (size_t)j * 8;
    }
    union { u16 u[8]; uint4 q; } o;
    #pragma unroll
    for (int i = 0; i < 8; ++i) o.u[i] = f2bf(s[i * 256]);
    *(uint4*)dst = o.q;
}

__device__ __forceinline__ void stageX(const u16* __restrict__ src,
                                       short* __restrict__ halX,
                                       int tid, int y0, int x0) {
    #pragma unroll 2
    for (int s = tid; s < 400; s += 256) {
        int pos = s >> 2, kb = s & 3;
        int hy = pos / 10, hx = pos - hy * 10;
        int gy = y0 + hy - 1, gx = x0 + hx - 1;
        short8v v = (short8v){0,0,0,0,0,0,0,0};
        if ((unsigned)gy < 64u && (unsigned)gx < 64u)
            v = *(const short8v*)&src[(((gy << 6) + gx) << 5) + (kb << 3)];
        *(short8v*)&halX[kb * 800 + pos * 8] = v;
    }
}

// ---- persistent fused conv + gates, all timesteps ----
// __launch_bounds__(256, 2): guarantee 2 blocks/CU capacity (guide §1) so a
// REGULAR launch of grid 512 = 2 x 256 CUs is fully co-resident.
__global__ __launch_bounds__(256, 2)
void lstm_all(const u16* __restrict__ xb,     // (8,10,64,64,32) bf16
              const u16* __restrict__ wt_in, const u16* __restrict__ wt_rk,
              const float* __restrict__ bias, const int* __restrict__ labels,
              u16* __restrict__ hb0, u16* __restrict__ hb1,  // h ring bufs
              float* __restrict__ out, unsigned* __restrict__ flags)
{
    // X halo @0: [kb4][100][8] (3200 shorts); H halo @3200: [kb8][HS=808]
    __shared__ short hal[HB + 8 * HS];   // 9664 shorts = 19,328 B

    const int tid  = threadIdx.x;
    const int lane = tid & 63;
    const int wq   = tid >> 6;                 // wave = f-slice 0..3
    const int b    = blockIdx.x >> 6;
    const int tile = blockIdx.x & 63;
    const int ty = tile >> 3, tx = tile & 7;
    const int y0 = ty << 3, x0 = tx << 3;
    const int g = labels[b];

    const int co_l = lane & 15;
    const int kbl  = lane >> 4;
    const int prow = (lane & 15) >> 3, pcol = lane & 7;
    const int f = (wq << 4) + co_l;

    float bv[4];
    #pragma unroll
    for (int n = 0; n < 4; ++n)
        bv[n] = bias[(g << 8) + (n << 6) + f];

    int aoffm[4];
    #pragma unroll
    for (int m = 0; m < 4; ++m)
        aoffm[m] = ((m << 1) + prow) * 10 + pcol;

    int poff[4][4], loff[4][4];
    #pragma unroll
    for (int m = 0; m < 4; ++m)
        #pragma unroll
        for (int rr = 0; rr < 4; ++rr) {
            int pf = (kbl << 2) + rr;
            int ly = (m << 1) + (pf >> 3);
            int lx = pf & 7;
            poff[m][rr] = ((((y0 + ly) << 6) + x0 + lx) << 6) + f;
            loff[m][rr] = HB + (f >> 3) * HS + ((ly + 1) * 10 + lx + 1) * 8 + (f & 7);
        }

    float cst[4][4];
    #pragma unroll
    for (int m = 0; m < 4; ++m)
        #pragma unroll
        for (int rr = 0; rr < 4; ++rr) cst[m][rr] = 0.0f;

    const u16* xsrc = xb + ((size_t)b * 10 << 17);
    float*     ob0  = out + ((size_t)b * 10 << 18);
    unsigned*  myfl = flags + (b << 6) + tile;

    // zero H halo (out-of-image ring cells stay 0 forever); stage X(0)
    for (int s = tid; s < 808; s += 256)
        *(short8v*)&hal[HB + s * 8] = (short8v){0,0,0,0,0,0,0,0};
    stageX(xsrc, hal, tid, y0, x0);
    __syncthreads();

    for (int t = 0; t < 10; ++t) {
        u16* hw = ((t & 1) ? hb1 : hb0) + ((size_t)b << 18);   // h(t)

        f32x4 acc[4][4];
        #pragma unroll
        for (int n = 0; n < 4; ++n)
            #pragma unroll
            for (int m = 0; m < 4; ++m)
                acc[m][n] = (f32x4){bv[n], bv[n], bv[n], bv[n]};

        // ---- phase X: 9 chunks (h-independent) ----
        #pragma unroll 3
        for (int tap = 0; tap < 9; ++tap) {
            const int koff = (tap / 3) * 10 + (tap % 3);
            const u16* wb = wt_in + (size_t)((((tap << 2) + kbl) << 8) + f) * 8;
            short8v bfr[4], af[4];
            #pragma unroll
            for (int n = 0; n < 4; ++n)
                bfr[n] = *(const short8v*)&wb[(size_t)n << 9];
            #pragma unroll
            for (int m = 0; m < 4; ++m)
                af[m] = *(const short8v*)&hal[kbl * 800 + (aoffm[m] + koff) * 8];
            #pragma unroll
            for (int m = 0; m < 4; ++m)
                #pragma unroll
                for (int n = 0; n < 4; ++n)
                    acc[m][n] = __builtin_amdgcn_mfma_f32_16x16x32_bf16(af[m], bfr[n], acc[m][n], 0, 0, 0);
        }

        if (t > 0) {
            // ---- poll 8 neighbor flags (wave 0): need h(t-1) exported ----
            if (tid < 64) {
                bool valid = false; int fidx = 0;
                if (tid < 8) {
                    int kk = tid + (tid >= 4);       // 0..8 skipping center
                    int nty = ty + kk / 3 - 1, ntx = tx + kk % 3 - 1;
                    valid = (unsigned)nty < 8u && (unsigned)ntx < 8u;
                    fidx = (b << 6) + (nty << 3) + ntx;
                }
                unsigned tgt = (unsigned)t;
                int guard = 0;
                for (;;) {
                    unsigned vv = tgt;
                    if (valid)
                        vv = __hip_atomic_load(flags + fidx, __ATOMIC_RELAXED,
                                               __HIP_MEMORY_SCOPE_SYSTEM);
                    if (__all(vv >= tgt)) break;
                    if (++guard > (1 << 19)) break;
                    __builtin_amdgcn_s_sleep(2);
                }
            }
            __syncthreads();   // neighbors' h(t-1) rings globally visible

            // ---- import ring h(t-1): 36 px x 8 units, sc0sc1 16B ----
            {
                const u16* hr = ((t & 1) ? hb0 : hb1) + ((size_t)b << 18);
                #pragma unroll
                for (int u = 0; u < 2; ++u) {
                    int s = tid + (u << 8);
                    if (s < 288) {
                        int posr = s >> 3, kb = s & 7;
                        int hy, hx;
                        if (posr < 10)      { hy = 0; hx = posr; }
                        else if (posr < 20) { hy = 9; hx = posr - 10; }
                        else { int v = posr - 20; hy = 1 + (v >> 1); hx = (v & 1) * 9; }
                        int gy = y0 + hy - 1, gx = x0 + hx - 1;
                        bool inb = (unsigned)gy < 64u && (unsigned)gx < 64u;
                        const u16* ga = inb ? (hr + (((gy << 6) + gx) << 6) + (kb << 3)) : hr;
                        u32x4 v;
                        asm volatile("global_load_dwordx4 %0, %1, off sc0 sc1"
                                     : "=v"(v) : "v"(ga) : "memory");
                        asm volatile("s_waitcnt vmcnt(0)" ::: "memory");
                        __builtin_amdgcn_sched_barrier(0);
                        if (!inb) v = (u32x4){0u, 0u, 0u, 0u};
                        *(u32x4*)&hal[HB + kb * HS + (hy * 10 + hx) * 8] = v;
                    }
                }
            }
            __syncthreads();   // ring in LDS

            // ---- phase H: 18 chunks ----
            #pragma unroll 3
            for (int c = 0; c < 18; ++c) {
                const int tap = c >> 1;
                const int koff = (tap / 3) * 10 + (tap % 3);
                const u16* wb = wt_rk + (size_t)(((((g * 18 + c) << 2) + kbl) << 8) + f) * 8;
                short8v bfr[4], af[4];
                #pragma unroll
                for (int n = 0; n < 4; ++n)
                    bfr[n] = *(const short8v*)&wb[(size_t)n << 9];
                const int abase = HB + (((c & 1) << 2) + kbl) * HS;
                #pragma unroll
                for (int m = 0; m < 4; ++m)
                    af[m] = *(const short8v*)&hal[abase + (aoffm[m] + koff) * 8];
                #pragma unroll
                for (int m = 0; m < 4; ++m)
                    #pragma unroll
                    for (int n = 0; n < 4; ++n)
                        acc[m][n] = __builtin_amdgcn_mfma_f32_16x16x32_bf16(af[m], bfr[n], acc[m][n], 0, 0, 0);
            }
        }
        __syncthreads();   // sync1: H-LDS (h(t-1)) reads complete

        // ---- gates + out store + h(t) interior -> LDS ----
        float* ob = ob0 + ((size_t)t << 18);
        #pragma unroll
        for (int m = 0; m < 4; ++m) {
            #pragma unroll
            for (int rr = 0; rr < 4; ++rr) {
                float zi = acc[m][0][rr], zf = acc[m][1][rr];
                float zg = acc[m][2][rr], zo = acc[m][3][rr];
                float cn = sigf(zf) * cst[m][rr] + sigf(zi) * tanhf_(zg);
                float hn = sigf(zo) * tanhf_(cn);
                cst[m][rr] = cn;
                ob[poff[m][rr]] = hn;
                hal[loff[m][rr]] = (short)f2bf(hn);
            }
        }
        __syncthreads();   // sync2: interior h(t) in LDS

        if (t < 9) {
            // ---- ring export: 28 boundary px x 8 units, sc0sc1 16B ----
            if (tid < 224) {
                int pxr = tid >> 3, kb = tid & 7;
                int dy, dx;
                if (pxr < 8)       { dy = 0; dx = pxr; }
                else if (pxr < 16) { dy = 7; dx = pxr - 8; }
                else { int v = pxr - 16; dy = 1 + (v >> 1); dx = (v & 1) * 7; }
                u32x4 v = *(const u32x4*)&hal[HB + kb * HS + ((dy + 1) * 10 + dx + 1) * 8];
                const u16* ga = hw + ((((y0 + dy) << 6) + x0 + dx) << 6) + (kb << 3);
                asm volatile("global_store_dwordx4 %0, %1, off sc0 sc1"
                             :: "v"(ga), "v"(v) : "memory");
            }
            // ---- stage X(t+1) (overlaps export latency) ----
            stageX(xsrc + ((size_t)(t + 1) << 17), hal, tid, y0, x0);
            asm volatile("s_waitcnt vmcnt(0)" ::: "memory");  // exports drained
            __syncthreads();   // sync3: exports + X(t+1) staged
            if (tid == 0)
                __hip_atomic_fetch_add(myfl, 1u, __ATOMIC_RELAXED,
                                       __HIP_MEMORY_SCOPE_SYSTEM);
        }
    }
}

extern "C" void kernel_launch(void* const* d_in, const int* in_sizes, int n_in,
                              void* d_out, int out_size, void* d_ws, size_t ws_size,
                              hipStream_t stream)
{
    const float* x    = (const float*)d_in[0];
    const int*   lbl  = (const int*)  d_in[1];
    const float* kern = (const float*)d_in[2];
    const float* rk   = (const float*)d_in[3];
    const float* bias = (const float*)d_in[4];
    float* out = (float*)d_out;

    // ws: xb 20.97MB | hb0 4.19 | hb1 4.19 | wt_in 0.147 | wt_rk 1.18 | flags 2KB
    u16* xb    = (u16*)d_ws;
    u16* hb0   = xb + 10485760;
    u16* hb1   = hb0 + 2097152;
    u16* wt_in = hb1 + 2097152;
    u16* wt_rk = wt_in + 73728;
    unsigned* flags = (unsigned*)(wt_rk + 589824);

    hipLaunchKernelGGL(prep_x, dim3(2048), dim3(256), 0, stream, x, xb);
    hipLaunchKernelGGL(prep_w, dim3(324), dim3(256), 0, stream,
                       kern, rk, wt_in, wt_rk, flags);

    // Regular launch; co-residency guaranteed by __launch_bounds__(256, 2)
    // capacity (2 blocks/CU x 256 CUs = 512 blocks exactly; guide §1).
    hipLaunchKernelGGL(lstm_all, dim3(512), dim3(256), 0, stream,
                       xb, wt_in, wt_rk, bias, lbl, hb0, hb1, out, flags);
}